// Round 1
// 482.389 us; speedup vs baseline: 1.0146x; 1.0146x over previous
//
#include <hip/hip_runtime.h>

typedef __attribute__((ext_vector_type(8))) short short8;
typedef __attribute__((ext_vector_type(4))) float f32x4;

#define SEQ 2048
#define BATCH 64
#define HID 512
#define ATT 512

__device__ __forceinline__ unsigned short f2bf(float f) {
  unsigned u = __float_as_uint(f);
  u += 0x7fffu + ((u >> 16) & 1u);   // round-to-nearest-even
  return (unsigned short)(u >> 16);
}

__device__ __forceinline__ void dma16(const void* g, void* l) {
  __builtin_amdgcn_global_load_lds(
      (const __attribute__((address_space(1))) unsigned int*)g,
      (__attribute__((address_space(3))) unsigned int*)l, 16, 0, 0);
}

// 8 fp32 -> 8 bf16 (RNE) in 4 VALU ops via v_cvt_pk_bf16_f32 (was ~32 bit-twiddle ops)
__device__ __forceinline__ short8 cvt8(float4 lo, float4 hi) {
  union { unsigned u[4]; short8 s; } r;
  asm("v_cvt_pk_bf16_f32 %0, %1, %2" : "=v"(r.u[0]) : "v"(lo.x), "v"(lo.y));
  asm("v_cvt_pk_bf16_f32 %0, %1, %2" : "=v"(r.u[1]) : "v"(lo.z), "v"(lo.w));
  asm("v_cvt_pk_bf16_f32 %0, %1, %2" : "=v"(r.u[2]) : "v"(hi.x), "v"(hi.y));
  asm("v_cvt_pk_bf16_f32 %0, %1, %2" : "=v"(r.u[3]) : "v"(hi.z), "v"(hi.w));
  return r.s;
}

// B-frag load straight to registers: uniform SGPR base (per-kb) + per-lane 32b voffset.
#define GLOADS(dst, voff, base, OFF) \
  asm volatile("global_load_dwordx4 %0, %1, %2 offset:" #OFF \
               : "=v"(dst) : "v"(voff), "s"(base))

// Counted vmcnt wait. "+v" ties the 4 live B-frags to the wait so every MFMA
// consuming them data-depends on it (rule-18 fence without sched_barrier(0)).
#define BWAIT(N, b0, b1, b2, b3) \
  asm volatile("s_waitcnt vmcnt(" #N ")" \
               : "+v"(b0), "+v"(b1), "+v"(b2), "+v"(b3) :: "memory")

// Pre-kernel: blocks 0..63 -> decT[a][b] = (W_t@dec_out[b]+b_t)[a] fp32 (transposed);
// blocks 64..127 -> wsb = W_s bf16 in the LDS-image permutation (bijective):
//   element (n=a, k=h): chunk c16=h>>5 (16384 shorts each); within chunk the 16B block
//   id is  (n>>4)*64 + ((h>>3)&3)*16 + (n&15)  -> short idx = block*8 + (h&7).
__global__ void bahdanau_pre(const float* __restrict__ dec_out,
                             const float* __restrict__ W_t,
                             const float* __restrict__ b_t,
                             const float* __restrict__ W_s,
                             unsigned short* __restrict__ wsb,
                             float* __restrict__ decT) {
  if (blockIdx.x < 64) {
    const int b = blockIdx.x;
    __shared__ float drow[HID];
    for (int i = threadIdx.x; i < HID; i += 256) drow[i] = dec_out[b * HID + i];
    __syncthreads();
    for (int a = threadIdx.x; a < ATT; a += 256) {
      const float4* wr = (const float4*)(W_t + (size_t)a * HID);
      float s0 = 0.f, s1 = 0.f, s2 = 0.f, s3 = 0.f;
#pragma unroll 4
      for (int j = 0; j < HID / 4; ++j) {
        float4 w = wr[j];
        s0 = fmaf(w.x, drow[4 * j + 0], s0);
        s1 = fmaf(w.y, drow[4 * j + 1], s1);
        s2 = fmaf(w.z, drow[4 * j + 2], s2);
        s3 = fmaf(w.w, drow[4 * j + 3], s3);
      }
      decT[a * BATCH + b] = (s0 + s1) + (s2 + s3) + b_t[a];
    }
  } else {
    const int cb = blockIdx.x - 64;
    const float4* src = (const float4*)W_s;
#pragma unroll
    for (int i = 0; i < 4; ++i) {
      int idx = cb * 1024 + i * 256 + threadIdx.x;   // float4 index over 512x512
      float4 v = src[idx];
      int a = idx >> 7;            // n (row of W_s)
      int h = (idx & 127) * 4;     // first k of the 4
      ushort4 o;
      o.x = f2bf(v.x); o.y = f2bf(v.y); o.z = f2bf(v.z); o.w = f2bf(v.w);
      int blk = (a >> 4) * 64 + ((h >> 3) & 3) * 16 + (a & 15);
      int dst = (h >> 5) * 16384 + blk * 8 + (h & 7);
      *(ushort4*)&wsb[dst] = o;
    }
  }
}

// Main: 2048 blocks x 512 thr (8 waves), one s per block, 2 blocks/CU.
// Counted-vmcnt pipeline (T3+T4), no __syncthreads in the K-loop:
//  - B-frags: register loads from the L2-resident wsb image (no cross-wave B reuse
//    exists -> LDS staging for B was pure overhead). Depth-1 prefetch.
//  - A: LDS-staged via global_load_lds (8x cross-wave reuse), 4 buffers, depth-2.
//  - Per-wave vmem issue order per iter kb: B(kb+1)x4 | A(kb+2) | wait | barrier.
//    Steady-state outstanding after the wait: {A(kb+1), B(kb+1)x4, A(kb+2)} = 6.
//    Tail: kb=14 -> 5, kb=15 -> 0.  Prologue order: A(0) | B(0)x4 | A(1).
//  - 4 A-buffers: dma(kb+2) targets tile kb-2's buffer; its readers finished
//    (trailing lgkmcnt(0)) before barrier(kb-1), which the writer already passed.
__global__ __launch_bounds__(512, 4)
void bahdanau_main(const float* __restrict__ enc,
                   const unsigned short* __restrict__ wsb,
                   const float* __restrict__ decT,
                   const float* __restrict__ v_a,
                   float* __restrict__ out) {
  __shared__ __align__(16) float Asm[4][2048];   // 4 x 8 KB A tiles
  __shared__ float partial[512];

  const int tid  = threadIdx.x;
  const int w    = tid >> 6;        // wave 0..7
  const int lane = tid & 63;
  const int c = lane & 15;
  const int q = lane >> 4;
  const int s = blockIdx.x;
  const int n0 = w * 64;

  const char* encB = (const char*)(enc + (size_t)s * 64 * HID);

  // A DMA per-lane global source for this (w, lane)
  const int am = (w & 3) * 16 + c;              // row m
  const int ag = q * 2 + (w >> 2);              // 4-float group in the 32-k chunk
  const char* aSrc = encB + am * 2048 + ag * 16;

  // B-frag (w,nt,q,c) byte address = kb*32768 + (w*256 + q*16 + c)*16 + nt*1024
  const unsigned voff = (unsigned)(w * 256 + q * 16 + c) * 16u;

  // acc init = dec_att (decT L2-warm): acc[mt][nt][r] = decT[n][mt*16+q*4+r]
  f32x4 acc[4][4];
#pragma unroll
  for (int nt = 0; nt < 4; ++nt)
#pragma unroll
    for (int mt = 0; mt < 4; ++mt)
      acc[mt][nt] = *(const f32x4*)(decT + (size_t)(n0 + nt * 16 + c) * 64 + mt * 16 + q * 4);

  // drain acc-init loads so the manual vmcnt ledger below is exact
  asm volatile("s_waitcnt vmcnt(0)" ::: "memory");

  short8 bf[2][4];

  // ---- prologue (ledger order): A(0) | B(0)x4 | A(1) ----
  dma16(aSrc, &Asm[0][w * 256]);
  GLOADS(bf[0][0], voff, wsb, 0);
  GLOADS(bf[0][1], voff, wsb, 1024);
  GLOADS(bf[0][2], voff, wsb, 2048);
  GLOADS(bf[0][3], voff, wsb, 3072);
  dma16(aSrc + 128, &Asm[1][w * 256]);

#pragma unroll
  for (int kb = 0; kb < 16; ++kb) {
    // issue B(kb+1) -> alternate register set
    if (kb + 1 < 16) {
      const unsigned short* bk = wsb + (size_t)(kb + 1) * 16384;
      GLOADS(bf[(kb + 1) & 1][0], voff, bk, 0);
      GLOADS(bf[(kb + 1) & 1][1], voff, bk, 1024);
      GLOADS(bf[(kb + 1) & 1][2], voff, bk, 2048);
      GLOADS(bf[(kb + 1) & 1][3], voff, bk, 3072);
    }
    // issue A(kb+2) -> buffer (kb+2)&3 (last read at iter kb-2; safe, see header)
    if (kb + 2 < 16)
      dma16(aSrc + (kb + 2) * 128, &Asm[(kb + 2) & 3][w * 256]);

    // own A(kb) staged + B(kb) landed (in-order drain covers A(kb): issued before B(kb))
    if (kb <= 13)      BWAIT(6, bf[kb & 1][0], bf[kb & 1][1], bf[kb & 1][2], bf[kb & 1][3]);
    else if (kb == 14) BWAIT(5, bf[kb & 1][0], bf[kb & 1][1], bf[kb & 1][2], bf[kb & 1][3]);
    else               BWAIT(0, bf[kb & 1][0], bf[kb & 1][1], bf[kb & 1][2], bf[kb & 1][3]);
    __builtin_amdgcn_s_barrier();   // cross-wave: whole A(kb) tile now in LDS

    // a-frags: A[m=mt*16+c][k=q*8..+7]: lo block mt*64+q*16+c, hi +256 blocks
    const float* Ac = &Asm[kb & 3][0];
#pragma unroll
    for (int mt = 0; mt < 4; ++mt) {
      float4 lo = *(const float4*)(Ac + (mt * 64 + q * 16 + c) * 4);
      float4 hi = *(const float4*)(Ac + (256 + mt * 64 + q * 16 + c) * 4);
      short8 af = cvt8(lo, hi);
#pragma unroll
      for (int nt = 0; nt < 4; ++nt)
        acc[mt][nt] = __builtin_amdgcn_mfma_f32_16x16x32_bf16(af, bf[kb & 1][nt], acc[mt][nt], 0, 0, 0);
    }
    // own ds_reads complete before this wave can reach the next barrier
    asm volatile("s_waitcnt lgkmcnt(0)" ::: "memory");
  }

  // ---- epilogue: score += v_a * tanh(acc) (dec folded in) ----
  float va[4];
#pragma unroll
  for (int nt = 0; nt < 4; ++nt) va[nt] = v_a[n0 + nt * 16 + c];

  float rowsum[4][4];
#pragma unroll
  for (int mt = 0; mt < 4; ++mt) {
#pragma unroll
    for (int r = 0; r < 4; ++r) {
      float sum = 0.f;
#pragma unroll
      for (int nt = 0; nt < 4; ++nt) {
        float x = acc[mt][nt][r];
        float e = __builtin_amdgcn_exp2f(x * 2.8853900817779268f);
        float t = 1.f - 2.f * __builtin_amdgcn_rcpf(e + 1.f);
        sum = fmaf(va[nt], t, sum);
      }
      rowsum[mt][r] = sum;
    }
  }

#pragma unroll
  for (int off = 1; off < 16; off <<= 1) {
#pragma unroll
    for (int mt = 0; mt < 4; ++mt)
#pragma unroll
      for (int r = 0; r < 4; ++r)
        rowsum[mt][r] += __shfl_xor(rowsum[mt][r], off, 64);
  }

  if (c == 0) {
#pragma unroll
    for (int mt = 0; mt < 4; ++mt)
#pragma unroll
      for (int r = 0; r < 4; ++r)
        partial[w * 64 + mt * 16 + q * 4 + r] = rowsum[mt][r];
  }
  __syncthreads();

  if (tid < 64) {
    float sum = 0.f;
#pragma unroll
    for (int ww = 0; ww < 8; ++ww) sum += partial[ww * 64 + tid];
    out[(size_t)tid * SEQ + s] = sum;
  }
}

extern "C" void kernel_launch(void* const* d_in, const int* in_sizes, int n_in,
                              void* d_out, int out_size, void* d_ws, size_t ws_size,
                              hipStream_t stream) {
  const float* dec_out = (const float*)d_in[0];   // (64, 512)
  const float* enc     = (const float*)d_in[1];   // (2048, 64, 512)
  const float* W_s     = (const float*)d_in[2];   // (512, 512)
  const float* W_t     = (const float*)d_in[3];   // (512, 512)
  const float* b_t     = (const float*)d_in[4];   // (512,)
  const float* v_a     = (const float*)d_in[5];   // (512,)
  float* out = (float*)d_out;                     // (64, 2048)

  unsigned short* wsb = (unsigned short*)d_ws;                     // 512 KB: W_s bf16 (image)
  float* decT = (float*)((char*)d_ws + (size_t)ATT * HID * 2);     // 128 KB: dec_att^T fp32

  bahdanau_pre<<<128, 256, 0, stream>>>(dec_out, W_t, b_t, W_s, wsb, decT);
  bahdanau_main<<<SEQ, 512, 0, stream>>>(enc, wsb, decT, v_a, out);
}

// Round 2
// 469.134 us; speedup vs baseline: 1.0432x; 1.0283x over previous
//
#include <hip/hip_runtime.h>

typedef __attribute__((ext_vector_type(8))) short short8;
typedef __attribute__((ext_vector_type(4))) float f32x4;

#define SEQ 2048
#define BATCH 64
#define HID 512
#define ATT 512

__device__ __forceinline__ unsigned short f2bf(float f) {
  unsigned u = __float_as_uint(f);
  u += 0x7fffu + ((u >> 16) & 1u);   // round-to-nearest-even
  return (unsigned short)(u >> 16);
}

__device__ __forceinline__ void dma16(const void* g, void* l) {
  __builtin_amdgcn_global_load_lds(
      (const __attribute__((address_space(1))) unsigned int*)g,
      (__attribute__((address_space(3))) unsigned int*)l, 16, 0, 0);
}

// 8 fp32 -> 8 bf16 (RNE) in 4 VALU ops via v_cvt_pk_bf16_f32
__device__ __forceinline__ short8 cvt8(float4 lo, float4 hi) {
  union { unsigned u[4]; short8 s; } r;
  asm("v_cvt_pk_bf16_f32 %0, %1, %2" : "=v"(r.u[0]) : "v"(lo.x), "v"(lo.y));
  asm("v_cvt_pk_bf16_f32 %0, %1, %2" : "=v"(r.u[1]) : "v"(lo.z), "v"(lo.w));
  asm("v_cvt_pk_bf16_f32 %0, %1, %2" : "=v"(r.u[2]) : "v"(hi.x), "v"(hi.y));
  asm("v_cvt_pk_bf16_f32 %0, %1, %2" : "=v"(r.u[3]) : "v"(hi.z), "v"(hi.w));
  return r.s;
}

// B-frag load straight to registers: uniform SGPR base (per-kb) + per-lane 32b voffset.
#define GLOADS(dst, voff, base, OFF) \
  asm volatile("global_load_dwordx4 %0, %1, %2 offset:" #OFF \
               : "=v"(dst) : "v"(voff), "s"(base))

// Counted vmcnt wait; "+v" re-defines the 4 live B-frags at the wait so every MFMA
// consuming them data-depends on it (rule-18 fence without sched_barrier).
#define BWAIT(N, b0, b1, b2, b3) \
  asm volatile("s_waitcnt vmcnt(" #N ")" \
               : "+v"(b0), "+v"(b1), "+v"(b2), "+v"(b3) :: "memory")

// Hand-asm LDS read: compiler sees no aliasing with global_load_lds -> no parasitic
// vmcnt insertion in the K-loop. IMM must constant-fold after unroll ("i").
#define DSREAD(dst, vaddr, IMM) \
  asm volatile("ds_read_b128 %0, %1 offset:%2" \
               : "=v"(dst) : "v"(vaddr), "i"(IMM))

// Pre-kernel: blocks 0..63 -> decT[a][b] = (W_t@dec_out[b]+b_t)[a] fp32 (transposed);
// blocks 64..127 -> wsb = W_s bf16 in the B-image permutation (bijective):
//   element (n=a, k=h): chunk c16=h>>5 (16384 shorts each); within chunk the 16B block
//   id is  (n>>4)*64 + ((h>>3)&3)*16 + (n&15)  -> short idx = block*8 + (h&7).
__global__ void bahdanau_pre(const float* __restrict__ dec_out,
                             const float* __restrict__ W_t,
                             const float* __restrict__ b_t,
                             const float* __restrict__ W_s,
                             unsigned short* __restrict__ wsb,
                             float* __restrict__ decT) {
  if (blockIdx.x < 64) {
    const int b = blockIdx.x;
    __shared__ float drow[HID];
    for (int i = threadIdx.x; i < HID; i += 256) drow[i] = dec_out[b * HID + i];
    __syncthreads();
    for (int a = threadIdx.x; a < ATT; a += 256) {
      const float4* wr = (const float4*)(W_t + (size_t)a * HID);
      float s0 = 0.f, s1 = 0.f, s2 = 0.f, s3 = 0.f;
#pragma unroll 4
      for (int j = 0; j < HID / 4; ++j) {
        float4 w = wr[j];
        s0 = fmaf(w.x, drow[4 * j + 0], s0);
        s1 = fmaf(w.y, drow[4 * j + 1], s1);
        s2 = fmaf(w.z, drow[4 * j + 2], s2);
        s3 = fmaf(w.w, drow[4 * j + 3], s3);
      }
      decT[a * BATCH + b] = (s0 + s1) + (s2 + s3) + b_t[a];
    }
  } else {
    const int cb = blockIdx.x - 64;
    const float4* src = (const float4*)W_s;
#pragma unroll
    for (int i = 0; i < 4; ++i) {
      int idx = cb * 1024 + i * 256 + threadIdx.x;   // float4 index over 512x512
      float4 v = src[idx];
      int a = idx >> 7;            // n (row of W_s)
      int h = (idx & 127) * 4;     // first k of the 4
      ushort4 o;
      o.x = f2bf(v.x); o.y = f2bf(v.y); o.z = f2bf(v.z); o.w = f2bf(v.w);
      int blk = (a >> 4) * 64 + ((h >> 3) & 3) * 16 + (a & 15);
      int dst = (h >> 5) * 16384 + blk * 8 + (h & 7);
      *(ushort4*)&wsb[dst] = o;
    }
  }
}

// Main: 2048 blocks x 512 thr (8 waves), one s per block, 1 block/CU (ILP > TLP bet).
//  - B-frags: register loads from the L2-resident wsb image, depth-1 prefetch.
//  - A: LDS-staged via global_load_lds, 8 buffers, DEPTH-4 prefetch.
//    A-DMA is row-contiguous: lane l of wave w fetches 16B of row m=w*8+(l>>3) at
//    in-row 16B-slot jsrc=(l&7)^(l>>3)  (XOR pre-swizzle on the GLOBAL source, rule #21;
//    8 contiguous 128B row-chunks per wave instead of 64 scattered 16B pieces).
//    LDS image: block m*8+j' holds global slot j = j'^(m&7); frag read applies the
//    same XOR -> 8 lanes per 4-bank group = LDS minimum cycles, no conflict penalty.
//  - Per-wave vmem issue order per iter kb: B(kb+1)x4 | A(kb+4) | wait | barrier.
//    Ledger (prologue A0..A3,B0x4): kb=0 ->5, 1..11 ->6, 12 ->5, 13..14 ->4, 15 ->0.
//  - 8 A-buffers: dma(kb+4) targets tile kb-4's buffer; live set is {kb-1..kb+4} = 6.
//  - Frag reads are hand-asm ds_read_b128 + lgkmcnt(0) + sched_barrier(0): no
//    compiler-scoreboard interference with the counted pipeline.
__global__ __launch_bounds__(512, 2)
void bahdanau_main(const float* __restrict__ enc,
                   const unsigned short* __restrict__ wsb,
                   const float* __restrict__ decT,
                   const float* __restrict__ v_a,
                   float* __restrict__ out) {
  __shared__ __align__(16) float Asm[8][2048];   // 8 x 8 KB A tiles (64 KB)
  __shared__ float partial[512];

  const int tid  = threadIdx.x;
  const int w    = tid >> 6;        // wave 0..7
  const int lane = tid & 63;
  const int c = lane & 15;
  const int q = lane >> 4;
  const int x7 = c & 7;
  const int s = blockIdx.x;
  const int n0 = w * 64;

  const char* encB = (const char*)(enc + (size_t)s * 64 * HID);

  // A-DMA per-lane global source: row m = w*8 + (l>>3), slot jsrc = (l&7)^(l>>3)
  const int am   = w * 8 + (lane >> 3);
  const int jsrc = (lane & 7) ^ (lane >> 3);
  const char* aSrc = encB + am * 2048 + jsrc * 16;   // + kb*128 per tile

  // B-frag (w,nt,q,c) byte address = kb*32768 + (w*256 + q*16 + c)*16 + nt*1024
  const unsigned voff = (unsigned)(w * 256 + q * 16 + c) * 16u;

  // LDS as3 byte offsets for the frag reads (XOR-swizzled slot)
  const unsigned lA = (unsigned)(size_t)(__attribute__((address_space(3))) char*)&Asm[0][0];
  const unsigned loOff = lA + (unsigned)(c * 128 + (((2 * q)    ) ^ x7) * 16);
  const unsigned hiOff = lA + (unsigned)(c * 128 + (((2 * q) | 1) ^ x7) * 16);

  // acc init = dec_att (decT L2-warm): acc[mt][nt][r] = decT[n][mt*16+q*4+r]
  f32x4 acc[4][4];
#pragma unroll
  for (int nt = 0; nt < 4; ++nt)
#pragma unroll
    for (int mt = 0; mt < 4; ++mt)
      acc[mt][nt] = *(const f32x4*)(decT + (size_t)(n0 + nt * 16 + c) * 64 + mt * 16 + q * 4);

  // drain acc-init loads so the manual vmcnt ledger below is exact
  asm volatile("s_waitcnt vmcnt(0)" ::: "memory");

  short8 bf[2][4];

  // ---- prologue (ledger order): A0 A1 A2 A3 | B0 x4 ----
  dma16(aSrc,       (char*)&Asm[0][0] + w * 1024);
  dma16(aSrc + 128, (char*)&Asm[1][0] + w * 1024);
  dma16(aSrc + 256, (char*)&Asm[2][0] + w * 1024);
  dma16(aSrc + 384, (char*)&Asm[3][0] + w * 1024);
  GLOADS(bf[0][0], voff, wsb, 0);
  GLOADS(bf[0][1], voff, wsb, 1024);
  GLOADS(bf[0][2], voff, wsb, 2048);
  GLOADS(bf[0][3], voff, wsb, 3072);

#pragma unroll
  for (int kb = 0; kb < 16; ++kb) {
    // issue B(kb+1) -> alternate register set
    if (kb + 1 < 16) {
      const unsigned short* bk = wsb + (size_t)(kb + 1) * 16384;
      GLOADS(bf[(kb + 1) & 1][0], voff, bk, 0);
      GLOADS(bf[(kb + 1) & 1][1], voff, bk, 1024);
      GLOADS(bf[(kb + 1) & 1][2], voff, bk, 2048);
      GLOADS(bf[(kb + 1) & 1][3], voff, bk, 3072);
    }
    // issue A(kb+4) -> buffer (kb+4)&7
    if (kb + 4 < 16)
      dma16(aSrc + (kb + 4) * 128, (char*)&Asm[(kb + 4) & 7][0] + w * 1024);

    // drain through {A(kb), B(kb)x4}; exact outstanding counts per the ledger
    if (kb == 0)       BWAIT(5, bf[kb & 1][0], bf[kb & 1][1], bf[kb & 1][2], bf[kb & 1][3]);
    else if (kb <= 11) BWAIT(6, bf[kb & 1][0], bf[kb & 1][1], bf[kb & 1][2], bf[kb & 1][3]);
    else if (kb == 12) BWAIT(5, bf[kb & 1][0], bf[kb & 1][1], bf[kb & 1][2], bf[kb & 1][3]);
    else if (kb <= 14) BWAIT(4, bf[kb & 1][0], bf[kb & 1][1], bf[kb & 1][2], bf[kb & 1][3]);
    else               BWAIT(0, bf[kb & 1][0], bf[kb & 1][1], bf[kb & 1][2], bf[kb & 1][3]);
    __builtin_amdgcn_s_barrier();   // cross-wave: whole A(kb) tile now in LDS

    // a-frags via hand-asm ds_read_b128 (immediate offset folds post-unroll)
    float4 lo0, hi0, lo1, hi1, lo2, hi2, lo3, hi3;
    DSREAD(lo0, loOff, ((kb & 7) * 8192 + 0 * 2048));
    DSREAD(hi0, hiOff, ((kb & 7) * 8192 + 0 * 2048));
    DSREAD(lo1, loOff, ((kb & 7) * 8192 + 1 * 2048));
    DSREAD(hi1, hiOff, ((kb & 7) * 8192 + 1 * 2048));
    DSREAD(lo2, loOff, ((kb & 7) * 8192 + 2 * 2048));
    DSREAD(hi2, hiOff, ((kb & 7) * 8192 + 2 * 2048));
    DSREAD(lo3, loOff, ((kb & 7) * 8192 + 3 * 2048));
    DSREAD(hi3, hiOff, ((kb & 7) * 8192 + 3 * 2048));
    asm volatile("s_waitcnt lgkmcnt(0)" ::: "memory");
    __builtin_amdgcn_sched_barrier(0);   // rule 18: nothing crosses the lgkm wait

    short8 af0 = cvt8(lo0, hi0);
    short8 af1 = cvt8(lo1, hi1);
    short8 af2 = cvt8(lo2, hi2);
    short8 af3 = cvt8(lo3, hi3);
#pragma unroll
    for (int nt = 0; nt < 4; ++nt) {
      acc[0][nt] = __builtin_amdgcn_mfma_f32_16x16x32_bf16(af0, bf[kb & 1][nt], acc[0][nt], 0, 0, 0);
      acc[1][nt] = __builtin_amdgcn_mfma_f32_16x16x32_bf16(af1, bf[kb & 1][nt], acc[1][nt], 0, 0, 0);
      acc[2][nt] = __builtin_amdgcn_mfma_f32_16x16x32_bf16(af2, bf[kb & 1][nt], acc[2][nt], 0, 0, 0);
      acc[3][nt] = __builtin_amdgcn_mfma_f32_16x16x32_bf16(af3, bf[kb & 1][nt], acc[3][nt], 0, 0, 0);
    }
  }

  // ---- epilogue: score += v_a * tanh(acc) (dec folded in) ----
  float va[4];
#pragma unroll
  for (int nt = 0; nt < 4; ++nt) va[nt] = v_a[n0 + nt * 16 + c];

  float rowsum[4][4];
#pragma unroll
  for (int mt = 0; mt < 4; ++mt) {
#pragma unroll
    for (int r = 0; r < 4; ++r) {
      float sum = 0.f;
#pragma unroll
      for (int nt = 0; nt < 4; ++nt) {
        float x = acc[mt][nt][r];
        float e = __builtin_amdgcn_exp2f(x * 2.8853900817779268f);
        float t = 1.f - 2.f * __builtin_amdgcn_rcpf(e + 1.f);
        sum = fmaf(va[nt], t, sum);
      }
      rowsum[mt][r] = sum;
    }
  }

#pragma unroll
  for (int off = 1; off < 16; off <<= 1) {
#pragma unroll
    for (int mt = 0; mt < 4; ++mt)
#pragma unroll
      for (int r = 0; r < 4; ++r)
        rowsum[mt][r] += __shfl_xor(rowsum[mt][r], off, 64);
  }

  if (c == 0) {
#pragma unroll
    for (int mt = 0; mt < 4; ++mt)
#pragma unroll
      for (int r = 0; r < 4; ++r)
        partial[w * 64 + mt * 16 + q * 4 + r] = rowsum[mt][r];
  }
  __syncthreads();

  if (tid < 64) {
    float sum = 0.f;
#pragma unroll
    for (int ww = 0; ww < 8; ++ww) sum += partial[ww * 64 + tid];
    out[(size_t)tid * SEQ + s] = sum;
  }
}

extern "C" void kernel_launch(void* const* d_in, const int* in_sizes, int n_in,
                              void* d_out, int out_size, void* d_ws, size_t ws_size,
                              hipStream_t stream) {
  const float* dec_out = (const float*)d_in[0];   // (64, 512)
  const float* enc     = (const float*)d_in[1];   // (2048, 64, 512)
  const float* W_s     = (const float*)d_in[2];   // (512, 512)
  const float* W_t     = (const float*)d_in[3];   // (512, 512)
  const float* b_t     = (const float*)d_in[4];   // (512,)
  const float* v_a     = (const float*)d_in[5];   // (512,)
  float* out = (float*)d_out;                     // (64, 2048)

  unsigned short* wsb = (unsigned short*)d_ws;                     // 512 KB: W_s bf16 (image)
  float* decT = (float*)((char*)d_ws + (size_t)ATT * HID * 2);     // 128 KB: dec_att^T fp32

  bahdanau_pre<<<128, 256, 0, stream>>>(dec_out, W_t, b_t, W_s, wsb, decT);
  bahdanau_main<<<SEQ, 512, 0, stream>>>(enc, wsb, decT, v_a, out);
}

// Round 5
// 459.541 us; speedup vs baseline: 1.0650x; 1.0209x over previous
//
#include <hip/hip_runtime.h>

typedef __attribute__((ext_vector_type(8))) short short8;
typedef __attribute__((ext_vector_type(4))) float f32x4;

#define SEQ 2048
#define BATCH 64
#define HID 512
#define ATT 512

__device__ __forceinline__ unsigned short f2bf(float f) {
  unsigned u = __float_as_uint(f);
  u += 0x7fffu + ((u >> 16) & 1u);   // round-to-nearest-even
  return (unsigned short)(u >> 16);
}

__device__ __forceinline__ void dma16(const void* g, void* l) {
  __builtin_amdgcn_global_load_lds(
      (const __attribute__((address_space(1))) unsigned int*)g,
      (__attribute__((address_space(3))) unsigned int*)l, 16, 0, 0);
}

// 8 fp32 -> 8 bf16 (RNE) in 4 VALU ops via v_cvt_pk_bf16_f32
__device__ __forceinline__ short8 cvt8(float4 lo, float4 hi) {
  union { unsigned u[4]; short8 s; } r;
  asm("v_cvt_pk_bf16_f32 %0, %1, %2" : "=v"(r.u[0]) : "v"(lo.x), "v"(lo.y));
  asm("v_cvt_pk_bf16_f32 %0, %1, %2" : "=v"(r.u[1]) : "v"(lo.z), "v"(lo.w));
  asm("v_cvt_pk_bf16_f32 %0, %1, %2" : "=v"(r.u[2]) : "v"(hi.x), "v"(hi.y));
  asm("v_cvt_pk_bf16_f32 %0, %1, %2" : "=v"(r.u[3]) : "v"(hi.z), "v"(hi.w));
  return r.s;
}

// B-frag load straight to registers: uniform SGPR base + per-lane 32b voffset.
#define GLOADS(dst, voff, base, OFF) \
  asm volatile("global_load_dwordx4 %0, %1, %2 offset:" #OFF \
               : "=v"(dst) : "v"(voff), "s"(base))

// Counted vmcnt wait; "+v" re-defines the 4 live B-frags at the wait so every MFMA
// consuming them data-depends on it.
#define BWAIT(N, b0, b1, b2, b3) \
  asm volatile("s_waitcnt vmcnt(" #N ")" \
               : "+v"(b0), "+v"(b1), "+v"(b2), "+v"(b3) :: "memory")

// Hand-asm LDS read (no compiler-scoreboard interference). IMM constant-folds.
#define DSREAD(dst, vaddr, IMM) \
  asm volatile("ds_read_b128 %0, %1 offset:%2" \
               : "=v"(dst) : "v"(vaddr), "i"(IMM))

// Pre-kernel: zero out; blocks 0..63 -> decT[a][b]=(W_t@dec_out[b]+b_t)[a] (transposed);
// blocks 64..127 -> wsb = W_s bf16 image:
//   (n=a,k=h): chunk h>>5 (16384 shorts); 16B block (n>>4)*64+((h>>3)&3)*16+(n&15),
//   short idx = block*8 + (h&7).
__global__ void bahdanau_pre(const float* __restrict__ dec_out,
                             const float* __restrict__ W_t,
                             const float* __restrict__ b_t,
                             const float* __restrict__ W_s,
                             unsigned short* __restrict__ wsb,
                             float* __restrict__ decT,
                             float* __restrict__ out) {
  // zero out (64x2048 f32 = 32768 float4 = 128 blk x 256 thr)
  ((float4*)out)[blockIdx.x * 256 + threadIdx.x] = make_float4(0.f, 0.f, 0.f, 0.f);

  if (blockIdx.x < 64) {
    const int b = blockIdx.x;
    __shared__ float drow[HID];
    for (int i = threadIdx.x; i < HID; i += 256) drow[i] = dec_out[b * HID + i];
    __syncthreads();
    for (int a = threadIdx.x; a < ATT; a += 256) {
      const float4* wr = (const float4*)(W_t + (size_t)a * HID);
      float s0 = 0.f, s1 = 0.f, s2 = 0.f, s3 = 0.f;
#pragma unroll 4
      for (int j = 0; j < HID / 4; ++j) {
        float4 w = wr[j];
        s0 = fmaf(w.x, drow[4 * j + 0], s0);
        s1 = fmaf(w.y, drow[4 * j + 1], s1);
        s2 = fmaf(w.z, drow[4 * j + 2], s2);
        s3 = fmaf(w.w, drow[4 * j + 3], s3);
      }
      decT[a * BATCH + b] = (s0 + s1) + (s2 + s3) + b_t[a];
    }
  } else {
    const int cb = blockIdx.x - 64;
    const float4* src = (const float4*)W_s;
#pragma unroll
    for (int i = 0; i < 4; ++i) {
      int idx = cb * 1024 + i * 256 + threadIdx.x;
      float4 v = src[idx];
      int a = idx >> 7;
      int h = (idx & 127) * 4;
      ushort4 o;
      o.x = f2bf(v.x); o.y = f2bf(v.y); o.z = f2bf(v.z); o.w = f2bf(v.w);
      int blk = (a >> 4) * 64 + ((h >> 3) & 3) * 16 + (a & 15);
      int dst = (h >> 5) * 16384 + blk * 8 + (h & 7);
      *(ushort4*)&wsb[dst] = o;
    }
  }
}

// Main: 4096 blocks x 256 thr (4 waves). block=(s,h): att cols h*256+w*64. 3 blocks/CU.
//  - K-loop: 8 groups x 2 tiles; 3 rotating group-buffers (48 KB); ONE barrier per group.
//  - B: register loads from L2-resident wsb, depth-1 prefetch.
//  - A: global_load_lds staged per group (4 dma16/wave: 2 tiles x 16 rows).
//    Row-contiguous global with XOR pre-swizzle: lane l -> row w*16+(l>>3) (+8 for d=1),
//    slot (l&7)^(l>>3); image block = m*8 + (j^(m&7)); read applies the same XOR.
//  - Stagger: tile order t_i=((s&7)*2+i)&15 de-correlates the shared-B hot-spot.
//  - Ledger (in-order vmcnt): per iter i (g=i>>1,j=i&1): issue B(t_{i+1})x4; if j==0
//    issue STAGE(g+2)x4. Steady wait vmcnt(8) leaves {DMA(g+2)x4, B(next)x4}:
//    buffer for group g is fully drained (all waves) at i=2g-2, one barrier before
//    its reads at i=2g.  Tail: i=12..14 -> vmcnt(4), i=15 -> vmcnt(0).
//  - WAR: STAGE(g+2) targets buffer (g+2)%3 = (g-1)%3, whose readers (group g-1)
//    drained their lgkmcnt before the barrier this wave just passed.
//  - Cross-block reduction: atomicAdd into pre-zeroed out (exactly 2 adds/element).
__global__ __launch_bounds__(256, 3)
void bahdanau_main(const float* __restrict__ enc,
                   const unsigned short* __restrict__ wsb,
                   const float* __restrict__ decT,
                   const float* __restrict__ v_a,
                   float* __restrict__ out) {
  __shared__ __align__(16) float Abuf[3][2][2048];   // 3 group-bufs x 2 tiles x 8KB
  __shared__ float partial[256];

  const int tid  = threadIdx.x;
  const int w    = tid >> 6;        // wave 0..3
  const int lane = tid & 63;
  const int c = lane & 15;
  const int q = lane >> 4;
  const int x7 = c & 7;
  const int bid = blockIdx.x;
  const int s = bid >> 1;
  const int h = bid & 1;
  const int n0 = h * 256 + w * 64;
  const int t0 = (s & 7) * 2;       // stagger start tile (even -> groups stay paired)

  const char* encB = (const char*)(enc + (size_t)s * 64 * HID);

  // A-DMA per-lane global source: row m = w*16 + (l>>3) (+8 for d=1),
  // slot jsrc = (l&7)^(l>>3)
  const int am   = w * 16 + (lane >> 3);
  const int jsrc = (lane & 7) ^ (lane >> 3);
  const char* aSrc = encB + am * 2048 + jsrc * 16;   // + t*128 per tile, +16384 for d=1

  // B-frag byte offset: ((h*4+w)*256 + q*16 + c)*16  (+ nt*1024, + t*32768 via base)
  const unsigned voff = (unsigned)(((h * 4 + w) * 256 + q * 16 + c) * 16);

  // LDS as3 byte offsets for frag reads (XOR-swizzled slot)
  const unsigned lA = (unsigned)(size_t)(__attribute__((address_space(3))) char*)&Abuf[0][0][0];
  const unsigned loOff = lA + (unsigned)(c * 128 + (((2 * q)    ) ^ x7) * 16);
  const unsigned hiOff = lA + (unsigned)(c * 128 + (((2 * q) | 1) ^ x7) * 16);

  // acc init = dec_att (decT L2-warm)
  f32x4 acc[4][4];
#pragma unroll
  for (int nt = 0; nt < 4; ++nt)
#pragma unroll
    for (int mt = 0; mt < 4; ++mt)
      acc[mt][nt] = *(const f32x4*)(decT + (size_t)(n0 + nt * 16 + c) * 64 + mt * 16 + q * 4);

  asm volatile("s_waitcnt vmcnt(0)" ::: "memory");   // ledger starts clean

  short8 bf[2][4];

  // STAGE group a -> buffer b: 4 dma16 (tile j in {0,1}, row-half d in {0,1})
#define STAGE(a, b) do { \
    const char* s_ = aSrc + (size_t)(((t0 + 2 * (a)) & 15) * 128); \
    char* d_ = (char*)&Abuf[(b)][0][0] + w * 2048; \
    dma16(s_,                d_); \
    dma16(s_ + 16384,        d_ + 1024); \
    dma16(s_ + 128,          d_ + 8192); \
    dma16(s_ + 128 + 16384,  d_ + 8192 + 1024); \
  } while (0)

#define LOADB(set, t_) do { \
    const unsigned short* bk_ = wsb + (size_t)(t_) * 16384; \
    GLOADS(bf[set][0], voff, bk_, 0); \
    GLOADS(bf[set][1], voff, bk_, 1024); \
    GLOADS(bf[set][2], voff, bk_, 2048); \
    GLOADS(bf[set][3], voff, bk_, 3072); \
  } while (0)

  // ---- prologue: DMA(g0), DMA(g1), B(t_0); drain DMA(g0); barrier ----
  STAGE(0, 0);
  STAGE(1, 1);
  LOADB(0, t0);
  asm volatile("s_waitcnt vmcnt(8)" ::: "memory");   // leaves {DMA(1)x4, B(0)x4}
  __builtin_amdgcn_s_barrier();

#pragma unroll
  for (int i = 0; i < 16; ++i) {
    const int g = i >> 1, j = i & 1, buf = (i >> 1) % 3;

    if (i + 1 < 16) LOADB((i + 1) & 1, (t0 + i + 1) & 15);
    if (j == 0 && g + 2 <= 7) STAGE(g + 2, (g + 2) % 3);

    if (i <= 11)      BWAIT(8, bf[i & 1][0], bf[i & 1][1], bf[i & 1][2], bf[i & 1][3]);
    else if (i <= 14) BWAIT(4, bf[i & 1][0], bf[i & 1][1], bf[i & 1][2], bf[i & 1][3]);
    else              BWAIT(0, bf[i & 1][0], bf[i & 1][1], bf[i & 1][2], bf[i & 1][3]);

    // a-frags: tile (buf, j), row mt*16+c, slots (2q)^x7 / (2q|1)^x7
    float4 lo0, hi0, lo1, hi1, lo2, hi2, lo3, hi3;
    DSREAD(lo0, loOff, (buf * 16384 + j * 8192 + 0 * 2048));
    DSREAD(hi0, hiOff, (buf * 16384 + j * 8192 + 0 * 2048));
    DSREAD(lo1, loOff, (buf * 16384 + j * 8192 + 1 * 2048));
    DSREAD(hi1, hiOff, (buf * 16384 + j * 8192 + 1 * 2048));
    DSREAD(lo2, loOff, (buf * 16384 + j * 8192 + 2 * 2048));
    DSREAD(hi2, hiOff, (buf * 16384 + j * 8192 + 2 * 2048));
    DSREAD(lo3, loOff, (buf * 16384 + j * 8192 + 3 * 2048));
    DSREAD(hi3, hiOff, (buf * 16384 + j * 8192 + 3 * 2048));
    asm volatile("s_waitcnt lgkmcnt(0)" ::: "memory");
    __builtin_amdgcn_sched_barrier(0);   // rule 18

    short8 af0 = cvt8(lo0, hi0);
    short8 af1 = cvt8(lo1, hi1);
    short8 af2 = cvt8(lo2, hi2);
    short8 af3 = cvt8(lo3, hi3);
#pragma unroll
    for (int nt = 0; nt < 4; ++nt) {
      acc[0][nt] = __builtin_amdgcn_mfma_f32_16x16x32_bf16(af0, bf[i & 1][nt], acc[0][nt], 0, 0, 0);
      acc[1][nt] = __builtin_amdgcn_mfma_f32_16x16x32_bf16(af1, bf[i & 1][nt], acc[1][nt], 0, 0, 0);
      acc[2][nt] = __builtin_amdgcn_mfma_f32_16x16x32_bf16(af2, bf[i & 1][nt], acc[2][nt], 0, 0, 0);
      acc[3][nt] = __builtin_amdgcn_mfma_f32_16x16x32_bf16(af3, bf[i & 1][nt], acc[3][nt], 0, 0, 0);
    }

    if (j == 1 && g < 7) __builtin_amdgcn_s_barrier();   // group end
  }
#undef STAGE
#undef LOADB

  // ---- epilogue: score += v_a * tanh(acc) ----
  float va[4];
#pragma unroll
  for (int nt = 0; nt < 4; ++nt) va[nt] = v_a[n0 + nt * 16 + c];

  float rowsum[4][4];
#pragma unroll
  for (int mt = 0; mt < 4; ++mt) {
#pragma unroll
    for (int r = 0; r < 4; ++r) {
      float sum = 0.f;
#pragma unroll
      for (int nt = 0; nt < 4; ++nt) {
        float x = acc[mt][nt][r];
        float e = __builtin_amdgcn_exp2f(x * 2.8853900817779268f);
        float t = 1.f - 2.f * __builtin_amdgcn_rcpf(e + 1.f);
        sum = fmaf(va[nt], t, sum);
      }
      rowsum[mt][r] = sum;
    }
  }

#pragma unroll
  for (int off = 1; off < 16; off <<= 1) {
#pragma unroll
    for (int mt = 0; mt < 4; ++mt)
#pragma unroll
      for (int r = 0; r < 4; ++r)
        rowsum[mt][r] += __shfl_xor(rowsum[mt][r], off, 64);
  }

  if (c == 0) {
#pragma unroll
    for (int mt = 0; mt < 4; ++mt)
#pragma unroll
      for (int r = 0; r < 4; ++r)
        partial[w * 64 + mt * 16 + q * 4 + r] = rowsum[mt][r];
  }
  __syncthreads();

  if (tid < 64) {
    float sum = 0.f;
#pragma unroll
    for (int ww = 0; ww < 4; ++ww) sum += partial[ww * 64 + tid];
    atomicAdd(&out[(size_t)tid * SEQ + s], sum);   // exactly 2 adds/element (h=0,1)
  }
}

extern "C" void kernel_launch(void* const* d_in, const int* in_sizes, int n_in,
                              void* d_out, int out_size, void* d_ws, size_t ws_size,
                              hipStream_t stream) {
  const float* dec_out = (const float*)d_in[0];   // (64, 512)
  const float* enc     = (const float*)d_in[1];   // (2048, 64, 512)
  const float* W_s     = (const float*)d_in[2];   // (512, 512)
  const float* W_t     = (const float*)d_in[3];   // (512, 512)
  const float* b_t     = (const float*)d_in[4];   // (512,)
  const float* v_a     = (const float*)d_in[5];   // (512,)
  float* out = (float*)d_out;                     // (64, 2048)

  unsigned short* wsb = (unsigned short*)d_ws;                     // 512 KB: W_s bf16 image
  float* decT = (float*)((char*)d_ws + (size_t)ATT * HID * 2);     // 128 KB: dec_att^T fp32

  bahdanau_pre<<<128, 256, 0, stream>>>(dec_out, W_t, b_t, W_s, wsb, decT, out);
  bahdanau_main<<<SEQ * 2, 256, 0, stream>>>(enc, wsb, decT, v_a, out);
}